// Round 3
// baseline (189.050 us; speedup 1.0000x reference)
//
#include <hip/hip_runtime.h>
#include <cstdint>
#include <cfloat>

typedef float v2f __attribute__((ext_vector_type(2)));

// Sample grid: round(linspace(0,63,16)) -- verified no .5 cases, fp32/fp64 agree.
__constant__ int c_smp[16] = {0,4,8,13,17,21,25,29,34,38,42,46,50,55,59,63};

// Problem constants
static constexpr int NB   = 32;    // batch
static constexpr int NC   = 64;    // C1 channels after unshuffle
static constexpr int NH   = 64;    // H1
static constexpr int NTOK = 4096;  // H1*W1
static constexpr int NM   = 256;   // samples
static constexpr int NK   = 3;     // neighbors

// ---------------------------------------------------------------------------
// Kernel PRE = k_xs (blocks 0..511) + k_wt (blocks 512..559). Bodies are
// bitwise identical to R8's k_xs / k_wt; only packaging changed (R9).
// ---------------------------------------------------------------------------
__global__ __launch_bounds__(256) void k_pre(const float* __restrict__ x,
                                             const float* __restrict__ w,
                                             float* __restrict__ wT,
                                             float* __restrict__ xs_t,
                                             float* __restrict__ xs_m) {
    __shared__ __align__(16) float rows[16][2][128];   // 16 KB (xs branch only)
    if (blockIdx.x >= NB * 16) {
        // ---- weight transpose: w[o][c][k] -> wT[k][c][o] ----
        int f = (blockIdx.x - NB * 16) * 256 + threadIdx.x;   // 0..12287
        float v = w[f];
        int o = f / 192, rem = f % 192;
        int c = rem / 3, k = rem % 3;
        wT[((size_t)k * 64 + c) * 64 + o] = v;
        return;
    }
    // ---- gather x_sample in two layouts. One block per (b, gi). ----
    int b = blockIdx.x >> 4, gi = blockIdx.x & 15;
    int hh = c_smp[gi];
    int t = threadIdx.x;
    const float* xb = x + (size_t)b * 16 * 128 * 128;
#pragma unroll
    for (int it = 0; it < 4; ++it) {
        int q = t + it * 256;          // 0..1023 float4 groups
        int c = q >> 6;
        int rem = q & 63;
        int sh = rem >> 5;
        int col = (rem & 31) * 4;
        float4 v = *(const float4*)(xb + ((size_t)c * 128 + (2 * hh + sh)) * 128 + col);
        *(float4*)&rows[c][sh][col] = v;
    }
    __syncthreads();
    // xs_t: thread t -> c1 = t>>2, gj group = (t&3)*4 .. +3
    {
        int c1 = t >> 2;
        int c = c1 >> 2, sh = (c1 >> 1) & 1, sw = c1 & 1;
        int gj0 = (t & 3) * 4;
        float4 v;
        v.x = rows[c][sh][2 * c_smp[gj0 + 0] + sw];
        v.y = rows[c][sh][2 * c_smp[gj0 + 1] + sw];
        v.z = rows[c][sh][2 * c_smp[gj0 + 2] + sw];
        v.w = rows[c][sh][2 * c_smp[gj0 + 3] + sw];
        *(float4*)&xs_t[((size_t)b * NC + c1) * NM + gi * 16 + gj0] = v;
    }
    // xs_m: thread t -> mloc = t>>4, c1 group = (t&15)*4 .. +3
    {
        int mloc = t >> 4, cg = t & 15;
        int w2 = 2 * c_smp[mloc];
        float4 v;
        v.x = rows[cg][0][w2];
        v.y = rows[cg][0][w2 + 1];
        v.z = rows[cg][1][w2];
        v.w = rows[cg][1][w2 + 1];
        *(float4*)&xs_m[((size_t)b * NM + gi * 16 + mloc) * NC + cg * 4] = v;
    }
}

// ---------------------------------------------------------------------------
// Kernel MID = k_dist (blocks 0..2047) + k_z (blocks 2048..2431, 4 jobs per
// block, one per 64-lane wave). k_z and k_dist are independent (both consume
// only k_pre outputs) but serialized on one stream as separate kernels; as
// one grid the 384 z-blocks fill k_dist's idle issue slots (achieved
// occupancy was only 27%) -> z runs ~free. All arithmetic bitwise identical
// to R8 (same op order, same stores) -> Z and idx unchanged.
// ---------------------------------------------------------------------------
static __device__ __forceinline__ unsigned long long packkey(float d, int m) {
    unsigned u = __float_as_uint(d);
    u ^= ((unsigned)((int)u >> 31)) | 0x80000000u;   // monotone float->uint
    return ((unsigned long long)u << 32) | (unsigned)m;
}

__global__ __launch_bounds__(256) void k_mid(const float* __restrict__ x,
                                             const float* __restrict__ xs_t,
                                             const float* __restrict__ xs_m,
                                             const float* __restrict__ wT,
                                             float* __restrict__ Z,
                                             int* __restrict__ idx) {
    __shared__ __align__(16) float att[16][64];    // 4 KB   A chunk [c][n]
    __shared__ __align__(16) float xsB[16][256];   // 16 KB  B chunk [c][perm(m)]
    __shared__ __align__(16) float m2l[256];
    __shared__ __align__(16) float n2l[64];

    if (blockIdx.x >= NB * 64) {
        // ---- k_z: Z[b][k][m][o] = sum_c wT[k][c][o] * xs_m[b][m][c] ----
        int job = (blockIdx.x - NB * 64) * 4 + (threadIdx.x >> 6);  // 0..1535
        int mg  = job & 15;
        int k   = (job >> 4) % 3;
        int b   = job / 48;
        int o   = threadIdx.x & 63;
        float wf[64];
#pragma unroll
        for (int c = 0; c < 64; ++c) wf[c] = wT[((size_t)k * 64 + c) * 64 + o];
        const float* xb = xs_m + (size_t)b * NM * NC;
        float* zb = Z + ((size_t)b * 3 + k) * NM * NC;
        for (int mm = 0; mm < 16; ++mm) {
            int m = mg * 16 + mm;
            const float* xr = xb + (size_t)m * NC;   // wave-uniform address
            float acc = 0.f;
#pragma unroll
            for (int c = 0; c < 64; ++c) acc = fmaf(wf[c], xr[c], acc);
            zb[(size_t)m * NC + o] = acc;            // coalesced over o
        }
        return;
    }

    // ---- k_dist: distances + top-3 selection (R8 body, unchanged) ----
    int b = blockIdx.x >> 6;
    int h = blockIdx.x & 63;
    int t = threadIdx.x;
    int r = t >> 4, cl = t & 15;     // token group 0..15, sample lane 0..15

    v2f acc2[4][8];
#pragma unroll
    for (int i = 0; i < 4; ++i)
#pragma unroll
        for (int j = 0; j < 8; ++j) acc2[i][j] = (v2f)(0.f);

    float m2acc = 0.f, n2acc = 0.f;
    const float* xb = x + (size_t)b * 16 * 128 * 128;
    const float* xsb = xs_t + (size_t)b * NC * NM;

    for (int kc = 0; kc < 4; ++kc) {
        __syncthreads();
        // A chunk: att[c1-kc*16][w] from x with unshuffle fold. float2 covers sw={0,1}.
#pragma unroll
        for (int it = 0; it < 2; ++it) {
            int i = t + it * 256;          // 0..511
            int p = i >> 6;                // 0..7 (c1 pair within chunk)
            int wcol = i & 63;
            int c1e = kc * 16 + p * 2;
            int c = c1e >> 2, sh = (c1e >> 1) & 1;
            const float* src = xb + ((size_t)c * 128 + (2 * h + sh)) * 128 + 2 * wcol;
            float2 v = *(const float2*)src;
            att[p * 2 + 0][wcol] = v.x;
            att[p * 2 + 1][wcol] = v.y;
        }
        // B chunk: float4 coalesced from xs_t; quad m4 -> slot (m4&3)*16 + (m4>>2).
#pragma unroll
        for (int it = 0; it < 4; ++it) {
            int g = t + it * 256;          // 0..1023
            int row = g >> 6;              // 0..15
            int m4 = g & 63;               // sample quad id
            int dst = ((((m4 & 3) << 4) | (m4 >> 2))) << 2;
            *(float4*)&xsB[row][dst] =
                *(const float4*)&xsb[(size_t)(kc * 16 + row) * NM + m4 * 4];
        }
        __syncthreads();

        // m2 / n2 partials (sequential ascending c, mul then add like np).
#pragma unroll
        for (int c = 0; c < 16; ++c) {
            float v = xsB[c][t];
            m2acc = __fadd_rn(m2acc, __fmul_rn(v, v));
        }
        if (t < 64) {
#pragma unroll
            for (int c = 0; c < 16; ++c) {
                float v = att[c][t];
                n2acc = __fadd_rn(n2acc, __fmul_rn(v, v));
            }
        }

        // dot accumulation: 4 tokens x 8 sample-pairs (16 samples), paired fma.
#pragma unroll
        for (int k = 0; k < 16; ++k) {
            float4 a0 = *(const float4*)&att[k][r * 4];
            float4 b0 = *(const float4*)&xsB[k][(0 * 16 + cl) * 4];
            float4 b1 = *(const float4*)&xsB[k][(1 * 16 + cl) * 4];
            float4 b2 = *(const float4*)&xsB[k][(2 * 16 + cl) * 4];
            float4 b3 = *(const float4*)&xsB[k][(3 * 16 + cl) * 4];
            v2f bp0 = {b0.x, b0.y}, bp1 = {b0.z, b0.w};
            v2f bp2 = {b1.x, b1.y}, bp3 = {b1.z, b1.w};
            v2f bp4 = {b2.x, b2.y}, bp5 = {b2.z, b2.w};
            v2f bp6 = {b3.x, b3.y}, bp7 = {b3.z, b3.w};
            float aa[4] = {a0.x, a0.y, a0.z, a0.w};
#pragma unroll
            for (int i = 0; i < 4; ++i) {
                v2f ai = {aa[i], aa[i]};
                acc2[i][0] = __builtin_elementwise_fma(ai, bp0, acc2[i][0]);
                acc2[i][1] = __builtin_elementwise_fma(ai, bp1, acc2[i][1]);
                acc2[i][2] = __builtin_elementwise_fma(ai, bp2, acc2[i][2]);
                acc2[i][3] = __builtin_elementwise_fma(ai, bp3, acc2[i][3]);
                acc2[i][4] = __builtin_elementwise_fma(ai, bp4, acc2[i][4]);
                acc2[i][5] = __builtin_elementwise_fma(ai, bp5, acc2[i][5]);
                acc2[i][6] = __builtin_elementwise_fma(ai, bp6, acc2[i][6]);
                acc2[i][7] = __builtin_elementwise_fma(ai, bp7, acc2[i][7]);
            }
        }
    }

    // inverse slot permutation for the m2 store:
    // float index f: slot=f>>2, e=f&3; cl=slot&15, q=slot>>4;
    // m = cl*16 + q*4 + e
    m2l[((t >> 2) & 15) * 16 + (t >> 6) * 4 + (t & 3)] = m2acc;
    if (t < 64) n2l[t] = n2acc;
    __syncthreads();

    // preload this thread's 16 m2 values once (consecutive -> b128 loads)
    float m2r[16];
#pragma unroll
    for (int j = 0; j < 16; ++j) m2r[j] = m2l[cl * 16 + j];

    // selection — fully unrolled so acc stays in VGPRs.
#pragma unroll
    for (int i = 0; i < 4; ++i) {
        int nloc = r * 4 + i;
        float n2v = n2l[nloc];
        float e0d = FLT_MAX, e1d = FLT_MAX, e2d = FLT_MAX;
        int e0m = 0x7fffffff, e1m = 0x7fffffff, e2m = 0x7fffffff;
        // local scan, ascending m => strict compares implement the index
        // tie-break exactly (stable insertion).
#pragma unroll
        for (int j = 0; j < 16; ++j) {
            float dv = acc2[i][j >> 1][j & 1];          // compile-time indices
            float t1 = __fadd_rn(n2v, m2r[j]);          // n2 + m2
            float d = __fadd_rn(t1, -2.0f * dv);        // - 2*dot (2*acc exact)
            int m = cl * 16 + j;
            if (d < e2d) {
                e2d = d; e2m = m;
                if (e2d < e1d) {
                    float td = e1d; int tm = e1m; e1d = e2d; e1m = e2m;
                    e2d = td; e2m = tm;
                    if (e1d < e0d) {
                        float sd = e0d; int sm = e0m; e0d = e1d; e0m = e1m;
                        e1d = sd; e1m = sm;
                    }
                }
            }
        }
        // pack to sortable u64 keys (local list is sorted ascending)
        unsigned long long k0 = packkey(e0d, e0m);
        unsigned long long k1 = packkey(e1d, e1m);
        unsigned long long k2 = packkey(e2d, e2m);
        // butterfly merge of sorted top-3 lists over 16 lanes (4 stages)
#pragma unroll
        for (int mask = 1; mask <= 8; mask <<= 1) {
            unsigned long long q0 = __shfl_xor(k0, mask);
            unsigned long long q1 = __shfl_xor(k1, mask);
            unsigned long long q2 = __shfl_xor(k2, mask);
            unsigned long long clo = k0 < q0 ? k0 : q0;
            unsigned long long chi = k0 < q0 ? q0 : k0;
            unsigned long long dlo = k1 < q1 ? k1 : q1;
            unsigned long long dhi = k1 < q1 ? q1 : k1;
            unsigned long long f2  = k2 < q2 ? k2 : q2;
            unsigned long long elo = chi < dlo ? chi : dlo;
            unsigned long long ehi = chi < dlo ? dlo : chi;
            unsigned long long g2  = dhi < f2 ? dhi : f2;
            k0 = clo;
            k1 = elo;
            k2 = ehi < g2 ? ehi : g2;
        }
        if (cl == 0) {
            int n = h * 64 + nloc;
            int* op = idx + ((size_t)b * NTOK + n) * NK;
            op[0] = (int)(unsigned)(k0 & 0xffffffffu);
            op[1] = (int)(unsigned)(k1 & 0xffffffffu);
            op[2] = (int)(unsigned)(k2 & 0xffffffffu);
        }
    }
}

// ---------------------------------------------------------------------------
// Kernel OUT: out = bias + Z[...,idx0,:] + Z[...,idx1,:] + Z[...,idx2,:],
// pixel-shuffled. Unchanged from R8.
// ---------------------------------------------------------------------------
__global__ __launch_bounds__(256) void k_out(const float* __restrict__ Z,
                                             const int* __restrict__ idx,
                                             const float* __restrict__ bias,
                                             float* __restrict__ out) {
    __shared__ float staged[64 * 65];
    int b = blockIdx.x >> 6, h = blockIdx.x & 63;
    int t = threadIdx.x;
    int o = t & 63, wv = t >> 6;
    float bv = bias[o];
    const float* zb = Z + (size_t)b * 3 * NM * NC;
    const int* ib = idx + (size_t)b * NTOK * NK;
    for (int ti = 0; ti < 16; ++ti) {
        int w = wv * 16 + ti;
        int n = h * 64 + w;
        const int* ip = ib + (size_t)n * NK;       // wave-uniform
        int i0 = ip[0], i1 = ip[1], i2 = ip[2];
        float v = bv + zb[(size_t)i0 * NC + o]
                     + zb[(size_t)(NM + i1) * NC + o]
                     + zb[(size_t)(2 * NM + i2) * NC + o];
        staged[o * 65 + w] = v;                    // (o+w)%32 banks: conflict-free
    }
    __syncthreads();
    float* ob = out + (size_t)b * 16 * 128 * 128;
#pragma unroll
    for (int it = 0; it < 16; ++it) {
        int flat = t + it * 256;                   // 0..4095
        int W = flat & 127, sh = (flat >> 7) & 1, cc = flat >> 8;
        int oo = cc * 4 + sh * 2 + (W & 1);
        ob[((size_t)cc * 128 + 2 * h + sh) * 128 + W] = staged[oo * 65 + (W >> 1)];
    }
}

// ---------------------------------------------------------------------------
extern "C" void kernel_launch(void* const* d_in, const int* in_sizes, int n_in,
                              void* d_out, int out_size, void* d_ws, size_t ws_size,
                              hipStream_t stream) {
    const float* x    = (const float*)d_in[0];
    const float* w    = (const float*)d_in[1];
    const float* bias = (const float*)d_in[2];
    float* out = (float*)d_out;
    float* ws  = (float*)d_ws;

    // workspace layout (floats):
    float* xs_t = ws;                          // 32*64*256   = 524288
    float* xs_m = ws + 524288;                 // 32*256*64   = 524288
    float* Z    = ws + 1048576;                // 32*3*256*64 = 1572864
    int*   idxb = (int*)(ws + 2621440);        // 32*4096*3   = 393216 ints
    float* wT   = ws + 3014656;                // 3*64*64     = 12288
    // total ~12.1 MB

    hipLaunchKernelGGL(k_pre, dim3(NB * 16 + 48),        dim3(256), 0, stream,
                       x, w, wT, xs_t, xs_m);
    hipLaunchKernelGGL(k_mid, dim3(NB * 64 + NB * 3 * 4), dim3(256), 0, stream,
                       x, xs_t, xs_m, wT, Z, idxb);
    hipLaunchKernelGGL(k_out, dim3(NB * 64),             dim3(256), 0, stream,
                       Z, idxb, bias, out);
}

// Round 4
// 172.715 us; speedup vs baseline: 1.0946x; 1.0946x over previous
//
#include <hip/hip_runtime.h>
#include <cstdint>
#include <cfloat>

typedef float v2f __attribute__((ext_vector_type(2)));

// Sample grid: round(linspace(0,63,16)) -- verified no .5 cases, fp32/fp64 agree.
__constant__ int c_smp[16] = {0,4,8,13,17,21,25,29,34,38,42,46,50,55,59,63};

// Problem constants
static constexpr int NB   = 32;    // batch
static constexpr int NC   = 64;    // C1 channels after unshuffle
static constexpr int NH   = 64;    // H1
static constexpr int NTOK = 4096;  // H1*W1
static constexpr int NM   = 256;   // samples
static constexpr int NK   = 3;     // neighbors

// ---------------------------------------------------------------------------
// Kernel PRE = k_xs (blocks 0..511) + k_wt (blocks 512..559).
// R10: xs_m output dropped entirely (k_z2 consumes xs_t instead) -> k_pre
// writes halve. xs_t body bitwise identical to R8.
// ---------------------------------------------------------------------------
__global__ __launch_bounds__(256) void k_pre(const float* __restrict__ x,
                                             const float* __restrict__ w,
                                             float* __restrict__ wT,
                                             float* __restrict__ xs_t) {
    __shared__ __align__(16) float rows[16][2][128];   // 16 KB (xs branch only)
    if (blockIdx.x >= NB * 16) {
        // ---- weight transpose: w[o][c][k] -> wT[k][c][o] ----
        int f = (blockIdx.x - NB * 16) * 256 + threadIdx.x;   // 0..12287
        float v = w[f];
        int o = f / 192, rem = f % 192;
        int c = rem / 3, k = rem % 3;
        wT[((size_t)k * 64 + c) * 64 + o] = v;
        return;
    }
    // ---- gather x_sample (token-major layout only). One block per (b, gi). ----
    int b = blockIdx.x >> 4, gi = blockIdx.x & 15;
    int hh = c_smp[gi];
    int t = threadIdx.x;
    const float* xb = x + (size_t)b * 16 * 128 * 128;
#pragma unroll
    for (int it = 0; it < 4; ++it) {
        int q = t + it * 256;          // 0..1023 float4 groups
        int c = q >> 6;
        int rem = q & 63;
        int sh = rem >> 5;
        int col = (rem & 31) * 4;
        float4 v = *(const float4*)(xb + ((size_t)c * 128 + (2 * hh + sh)) * 128 + col);
        *(float4*)&rows[c][sh][col] = v;
    }
    __syncthreads();
    // xs_t: thread t -> c1 = t>>2, gj group = (t&3)*4 .. +3
    {
        int c1 = t >> 2;
        int c = c1 >> 2, sh = (c1 >> 1) & 1, sw = c1 & 1;
        int gj0 = (t & 3) * 4;
        float4 v;
        v.x = rows[c][sh][2 * c_smp[gj0 + 0] + sw];
        v.y = rows[c][sh][2 * c_smp[gj0 + 1] + sw];
        v.z = rows[c][sh][2 * c_smp[gj0 + 2] + sw];
        v.w = rows[c][sh][2 * c_smp[gj0 + 3] + sw];
        *(float4*)&xs_t[((size_t)b * NC + c1) * NM + gi * 16 + gj0] = v;
    }
}

// ---------------------------------------------------------------------------
// Kernel Z2 (R10): Z[b][k][m][o] = sum_c wT[k][c][o] * xs[b][m][c], reading
// X from xs_t[b][c][m]. Replaces R8's latency-bound k_z (64-thr blocks, 6
// waves/CU, 64-deep dependent fma chains, ~40-45 us) with a register-tiled
// mini-GEMM: 384 blocks x 256 thr, W staged in LDS once, X in 16c chunks,
// each thread a 4m x 4o tile. Per output the fma sequence is acc=0 then
// fmaf over c ascending 0..63 -- identical op order to R8's k_z -> Z
// bitwise identical.
// ---------------------------------------------------------------------------
__global__ __launch_bounds__(256) void k_z2(const float* __restrict__ xs_t,
                                            const float* __restrict__ wT,
                                            float* __restrict__ Z) {
    __shared__ __align__(16) float wL[64][64];    // 16 KB  W[c][o]
    __shared__ __align__(16) float xt[16][64];    // 4 KB   X chunk [c][m-local]
    int bid = blockIdx.x;          // 32b * 3k * 4mq = 384
    int mq = bid & 3;
    int k  = (bid >> 2) % 3;
    int b  = bid / 12;
    int t  = threadIdx.x;
    int mg = t >> 4, og = t & 15;  // thread tile: m = mq*64+mg*4+i, o = og*4+j

    // stage W: wT[k] is 4096 floats, flat float4-coalesced.
#pragma unroll
    for (int it = 0; it < 4; ++it) {
        int q = t + it * 256;            // float4 group 0..1023
        int c = q >> 4;
        int o4 = (q & 15) * 4;
        *(float4*)&wL[c][o4] = *(const float4*)&wT[(size_t)k * 4096 + q * 4];
    }

    v2f acc[4][2];
#pragma unroll
    for (int i = 0; i < 4; ++i) { acc[i][0] = (v2f)(0.f); acc[i][1] = (v2f)(0.f); }

    for (int cc = 0; cc < 4; ++cc) {
        __syncthreads();   // W ready (first iter) / previous chunk consumed
        {
            int c = t >> 4, m4 = (t & 15) * 4;
            *(float4*)&xt[c][m4] =
                *(const float4*)&xs_t[((size_t)b * NC + cc * 16 + c) * NM + mq * 64 + m4];
        }
        __syncthreads();
#pragma unroll
        for (int c = 0; c < 16; ++c) {
            float4 a4 = *(const float4*)&xt[c][mg * 4];
            float4 b4 = *(const float4*)&wL[cc * 16 + c][og * 4];
            v2f bp0 = {b4.x, b4.y}, bp1 = {b4.z, b4.w};
            float aa[4] = {a4.x, a4.y, a4.z, a4.w};
#pragma unroll
            for (int i = 0; i < 4; ++i) {
                v2f ai = {aa[i], aa[i]};
                acc[i][0] = __builtin_elementwise_fma(ai, bp0, acc[i][0]);
                acc[i][1] = __builtin_elementwise_fma(ai, bp1, acc[i][1]);
            }
        }
    }

    float* zb = Z + (((size_t)b * 3 + k) * NM + mq * 64) * NC;
#pragma unroll
    for (int i = 0; i < 4; ++i) {
        int m = mg * 4 + i;
        float4 v = {acc[i][0][0], acc[i][0][1], acc[i][1][0], acc[i][1][1]};
        *(float4*)&zb[(size_t)m * NC + og * 4] = v;   // coalesced over og
    }
}

// ---------------------------------------------------------------------------
// Kernel 3: distances + top-3 selection. R8 body verbatim (89 us, VGPR 68);
// R9's grid-fusion with k_z reverted -- the z-branch's wf[64] pushed the
// fused kernel to VGPR 112 and cost 50 us of dist throughput.
// ---------------------------------------------------------------------------
static __device__ __forceinline__ unsigned long long packkey(float d, int m) {
    unsigned u = __float_as_uint(d);
    u ^= ((unsigned)((int)u >> 31)) | 0x80000000u;   // monotone float->uint
    return ((unsigned long long)u << 32) | (unsigned)m;
}

__global__ __launch_bounds__(256) void k_dist(const float* __restrict__ x,
                                              const float* __restrict__ xs_t,
                                              int* __restrict__ idx) {
    __shared__ __align__(16) float att[16][64];    // 4 KB   A chunk [c][n]
    __shared__ __align__(16) float xsB[16][256];   // 16 KB  B chunk [c][perm(m)]
    __shared__ __align__(16) float m2l[256];
    __shared__ __align__(16) float n2l[64];

    int b = blockIdx.x >> 6;
    int h = blockIdx.x & 63;
    int t = threadIdx.x;
    int r = t >> 4, cl = t & 15;     // token group 0..15, sample lane 0..15

    v2f acc2[4][8];
#pragma unroll
    for (int i = 0; i < 4; ++i)
#pragma unroll
        for (int j = 0; j < 8; ++j) acc2[i][j] = (v2f)(0.f);

    float m2acc = 0.f, n2acc = 0.f;
    const float* xb = x + (size_t)b * 16 * 128 * 128;
    const float* xsb = xs_t + (size_t)b * NC * NM;

    for (int kc = 0; kc < 4; ++kc) {
        __syncthreads();
        // A chunk: att[c1-kc*16][w] from x with unshuffle fold. float2 covers sw={0,1}.
#pragma unroll
        for (int it = 0; it < 2; ++it) {
            int i = t + it * 256;          // 0..511
            int p = i >> 6;                // 0..7 (c1 pair within chunk)
            int wcol = i & 63;
            int c1e = kc * 16 + p * 2;
            int c = c1e >> 2, sh = (c1e >> 1) & 1;
            const float* src = xb + ((size_t)c * 128 + (2 * h + sh)) * 128 + 2 * wcol;
            float2 v = *(const float2*)src;
            att[p * 2 + 0][wcol] = v.x;
            att[p * 2 + 1][wcol] = v.y;
        }
        // B chunk: float4 coalesced from xs_t; quad m4 -> slot (m4&3)*16 + (m4>>2).
#pragma unroll
        for (int it = 0; it < 4; ++it) {
            int g = t + it * 256;          // 0..1023
            int row = g >> 6;              // 0..15
            int m4 = g & 63;               // sample quad id
            int dst = ((((m4 & 3) << 4) | (m4 >> 2))) << 2;
            *(float4*)&xsB[row][dst] =
                *(const float4*)&xsb[(size_t)(kc * 16 + row) * NM + m4 * 4];
        }
        __syncthreads();

        // m2 / n2 partials (sequential ascending c, mul then add like np).
#pragma unroll
        for (int c = 0; c < 16; ++c) {
            float v = xsB[c][t];
            m2acc = __fadd_rn(m2acc, __fmul_rn(v, v));
        }
        if (t < 64) {
#pragma unroll
            for (int c = 0; c < 16; ++c) {
                float v = att[c][t];
                n2acc = __fadd_rn(n2acc, __fmul_rn(v, v));
            }
        }

        // dot accumulation: 4 tokens x 8 sample-pairs (16 samples), paired fma.
#pragma unroll
        for (int k = 0; k < 16; ++k) {
            float4 a0 = *(const float4*)&att[k][r * 4];
            float4 b0 = *(const float4*)&xsB[k][(0 * 16 + cl) * 4];
            float4 b1 = *(const float4*)&xsB[k][(1 * 16 + cl) * 4];
            float4 b2 = *(const float4*)&xsB[k][(2 * 16 + cl) * 4];
            float4 b3 = *(const float4*)&xsB[k][(3 * 16 + cl) * 4];
            v2f bp0 = {b0.x, b0.y}, bp1 = {b0.z, b0.w};
            v2f bp2 = {b1.x, b1.y}, bp3 = {b1.z, b1.w};
            v2f bp4 = {b2.x, b2.y}, bp5 = {b2.z, b2.w};
            v2f bp6 = {b3.x, b3.y}, bp7 = {b3.z, b3.w};
            float aa[4] = {a0.x, a0.y, a0.z, a0.w};
#pragma unroll
            for (int i = 0; i < 4; ++i) {
                v2f ai = {aa[i], aa[i]};
                acc2[i][0] = __builtin_elementwise_fma(ai, bp0, acc2[i][0]);
                acc2[i][1] = __builtin_elementwise_fma(ai, bp1, acc2[i][1]);
                acc2[i][2] = __builtin_elementwise_fma(ai, bp2, acc2[i][2]);
                acc2[i][3] = __builtin_elementwise_fma(ai, bp3, acc2[i][3]);
                acc2[i][4] = __builtin_elementwise_fma(ai, bp4, acc2[i][4]);
                acc2[i][5] = __builtin_elementwise_fma(ai, bp5, acc2[i][5]);
                acc2[i][6] = __builtin_elementwise_fma(ai, bp6, acc2[i][6]);
                acc2[i][7] = __builtin_elementwise_fma(ai, bp7, acc2[i][7]);
            }
        }
    }

    // inverse slot permutation for the m2 store:
    // float index f: slot=f>>2, e=f&3; cl=slot&15, q=slot>>4;
    // m = cl*16 + q*4 + e
    m2l[((t >> 2) & 15) * 16 + (t >> 6) * 4 + (t & 3)] = m2acc;
    if (t < 64) n2l[t] = n2acc;
    __syncthreads();

    // preload this thread's 16 m2 values once (consecutive -> b128 loads)
    float m2r[16];
#pragma unroll
    for (int j = 0; j < 16; ++j) m2r[j] = m2l[cl * 16 + j];

    // selection — fully unrolled so acc stays in VGPRs.
#pragma unroll
    for (int i = 0; i < 4; ++i) {
        int nloc = r * 4 + i;
        float n2v = n2l[nloc];
        float e0d = FLT_MAX, e1d = FLT_MAX, e2d = FLT_MAX;
        int e0m = 0x7fffffff, e1m = 0x7fffffff, e2m = 0x7fffffff;
        // local scan, ascending m => strict compares implement the index
        // tie-break exactly (stable insertion).
#pragma unroll
        for (int j = 0; j < 16; ++j) {
            float dv = acc2[i][j >> 1][j & 1];          // compile-time indices
            float t1 = __fadd_rn(n2v, m2r[j]);          // n2 + m2
            float d = __fadd_rn(t1, -2.0f * dv);        // - 2*dot (2*acc exact)
            int m = cl * 16 + j;
            if (d < e2d) {
                e2d = d; e2m = m;
                if (e2d < e1d) {
                    float td = e1d; int tm = e1m; e1d = e2d; e1m = e2m;
                    e2d = td; e2m = tm;
                    if (e1d < e0d) {
                        float sd = e0d; int sm = e0m; e0d = e1d; e0m = e1m;
                        e1d = sd; e1m = sm;
                    }
                }
            }
        }
        // pack to sortable u64 keys (local list is sorted ascending)
        unsigned long long k0 = packkey(e0d, e0m);
        unsigned long long k1 = packkey(e1d, e1m);
        unsigned long long k2 = packkey(e2d, e2m);
        // butterfly merge of sorted top-3 lists over 16 lanes (4 stages)
#pragma unroll
        for (int mask = 1; mask <= 8; mask <<= 1) {
            unsigned long long q0 = __shfl_xor(k0, mask);
            unsigned long long q1 = __shfl_xor(k1, mask);
            unsigned long long q2 = __shfl_xor(k2, mask);
            unsigned long long clo = k0 < q0 ? k0 : q0;
            unsigned long long chi = k0 < q0 ? q0 : k0;
            unsigned long long dlo = k1 < q1 ? k1 : q1;
            unsigned long long dhi = k1 < q1 ? q1 : k1;
            unsigned long long f2  = k2 < q2 ? k2 : q2;
            unsigned long long elo = chi < dlo ? chi : dlo;
            unsigned long long ehi = chi < dlo ? dlo : chi;
            unsigned long long g2  = dhi < f2 ? dhi : f2;
            k0 = clo;
            k1 = elo;
            k2 = ehi < g2 ? ehi : g2;
        }
        if (cl == 0) {
            int n = h * 64 + nloc;
            int* op = idx + ((size_t)b * NTOK + n) * NK;
            op[0] = (int)(unsigned)(k0 & 0xffffffffu);
            op[1] = (int)(unsigned)(k1 & 0xffffffffu);
            op[2] = (int)(unsigned)(k2 & 0xffffffffu);
        }
    }
}

// ---------------------------------------------------------------------------
// Kernel 4: out = bias + Z[...,idx0,:] + Z[...,idx1,:] + Z[...,idx2,:],
// pixel-shuffled. Unchanged from R8.
// ---------------------------------------------------------------------------
__global__ __launch_bounds__(256) void k_out(const float* __restrict__ Z,
                                             const int* __restrict__ idx,
                                             const float* __restrict__ bias,
                                             float* __restrict__ out) {
    __shared__ float staged[64 * 65];
    int b = blockIdx.x >> 6, h = blockIdx.x & 63;
    int t = threadIdx.x;
    int o = t & 63, wv = t >> 6;
    float bv = bias[o];
    const float* zb = Z + (size_t)b * 3 * NM * NC;
    const int* ib = idx + (size_t)b * NTOK * NK;
    for (int ti = 0; ti < 16; ++ti) {
        int w = wv * 16 + ti;
        int n = h * 64 + w;
        const int* ip = ib + (size_t)n * NK;       // wave-uniform
        int i0 = ip[0], i1 = ip[1], i2 = ip[2];
        float v = bv + zb[(size_t)i0 * NC + o]
                     + zb[(size_t)(NM + i1) * NC + o]
                     + zb[(size_t)(2 * NM + i2) * NC + o];
        staged[o * 65 + w] = v;                    // (o+w)%32 banks: conflict-free
    }
    __syncthreads();
    float* ob = out + (size_t)b * 16 * 128 * 128;
#pragma unroll
    for (int it = 0; it < 16; ++it) {
        int flat = t + it * 256;                   // 0..4095
        int W = flat & 127, sh = (flat >> 7) & 1, cc = flat >> 8;
        int oo = cc * 4 + sh * 2 + (W & 1);
        ob[((size_t)cc * 128 + 2 * h + sh) * 128 + W] = staged[oo * 65 + (W >> 1)];
    }
}

// ---------------------------------------------------------------------------
extern "C" void kernel_launch(void* const* d_in, const int* in_sizes, int n_in,
                              void* d_out, int out_size, void* d_ws, size_t ws_size,
                              hipStream_t stream) {
    const float* x    = (const float*)d_in[0];
    const float* w    = (const float*)d_in[1];
    const float* bias = (const float*)d_in[2];
    float* out = (float*)d_out;
    float* ws  = (float*)d_ws;

    // workspace layout (floats):
    float* xs_t = ws;                          // 32*64*256   = 524288
    float* Z    = ws + 524288;                 // 32*3*256*64 = 1572864
    int*   idxb = (int*)(ws + 2097152);        // 32*4096*3   = 393216 ints
    float* wT   = ws + 2490368;                // 3*64*64     = 12288
    // total ~10 MB

    hipLaunchKernelGGL(k_pre,  dim3(NB * 16 + 48), dim3(256), 0, stream,
                       x, w, wT, xs_t);
    hipLaunchKernelGGL(k_z2,   dim3(NB * 3 * 4),   dim3(256), 0, stream,
                       xs_t, wT, Z);
    hipLaunchKernelGGL(k_dist, dim3(NB * 64),      dim3(256), 0, stream,
                       x, xs_t, idxb);
    hipLaunchKernelGGL(k_out,  dim3(NB * 64),      dim3(256), 0, stream,
                       Z, idxb, bias, out);
}

// Round 5
// 165.212 us; speedup vs baseline: 1.1443x; 1.0454x over previous
//
#include <hip/hip_runtime.h>
#include <cstdint>
#include <cfloat>

typedef float v2f __attribute__((ext_vector_type(2)));

// Sample grid: round(linspace(0,63,16)) -- verified no .5 cases, fp32/fp64 agree.
__constant__ int c_smp[16] = {0,4,8,13,17,21,25,29,34,38,42,46,50,55,59,63};

// Problem constants
static constexpr int NB   = 32;    // batch
static constexpr int NC   = 64;    // C1 channels after unshuffle
static constexpr int NH   = 64;    // H1
static constexpr int NTOK = 4096;  // H1*W1
static constexpr int NM   = 256;   // samples
static constexpr int NK   = 3;     // neighbors

// ---------------------------------------------------------------------------
// Kernel PRE = k_xs (blocks 0..511) + k_wt (blocks 512..559). Unchanged R10.
// ---------------------------------------------------------------------------
__global__ __launch_bounds__(256) void k_pre(const float* __restrict__ x,
                                             const float* __restrict__ w,
                                             float* __restrict__ wT,
                                             float* __restrict__ xs_t) {
    __shared__ __align__(16) float rows[16][2][128];   // 16 KB (xs branch only)
    if (blockIdx.x >= NB * 16) {
        // ---- weight transpose: w[o][c][k] -> wT[k][c][o] ----
        int f = (blockIdx.x - NB * 16) * 256 + threadIdx.x;   // 0..12287
        float v = w[f];
        int o = f / 192, rem = f % 192;
        int c = rem / 3, k = rem % 3;
        wT[((size_t)k * 64 + c) * 64 + o] = v;
        return;
    }
    // ---- gather x_sample (token-major layout only). One block per (b, gi). ----
    int b = blockIdx.x >> 4, gi = blockIdx.x & 15;
    int hh = c_smp[gi];
    int t = threadIdx.x;
    const float* xb = x + (size_t)b * 16 * 128 * 128;
#pragma unroll
    for (int it = 0; it < 4; ++it) {
        int q = t + it * 256;          // 0..1023 float4 groups
        int c = q >> 6;
        int rem = q & 63;
        int sh = rem >> 5;
        int col = (rem & 31) * 4;
        float4 v = *(const float4*)(xb + ((size_t)c * 128 + (2 * hh + sh)) * 128 + col);
        *(float4*)&rows[c][sh][col] = v;
    }
    __syncthreads();
    // xs_t: thread t -> c1 = t>>2, gj group = (t&3)*4 .. +3
    {
        int c1 = t >> 2;
        int c = c1 >> 2, sh = (c1 >> 1) & 1, sw = c1 & 1;
        int gj0 = (t & 3) * 4;
        float4 v;
        v.x = rows[c][sh][2 * c_smp[gj0 + 0] + sw];
        v.y = rows[c][sh][2 * c_smp[gj0 + 1] + sw];
        v.z = rows[c][sh][2 * c_smp[gj0 + 2] + sw];
        v.w = rows[c][sh][2 * c_smp[gj0 + 3] + sw];
        *(float4*)&xs_t[((size_t)b * NC + c1) * NM + gi * 16 + gj0] = v;
    }
}

// ---------------------------------------------------------------------------
// Kernel Z2 (R10, unchanged): Z[b][k][m][o] = sum_c wT[k][c][o]*xs[b][m][c].
// Register-tiled mini-GEMM; per-output fma order identical to original k_z.
// ---------------------------------------------------------------------------
__global__ __launch_bounds__(256) void k_z2(const float* __restrict__ xs_t,
                                            const float* __restrict__ wT,
                                            float* __restrict__ Z) {
    __shared__ __align__(16) float wL[64][64];    // 16 KB  W[c][o]
    __shared__ __align__(16) float xt[16][64];    // 4 KB   X chunk [c][m-local]
    int bid = blockIdx.x;          // 32b * 3k * 4mq = 384
    int mq = bid & 3;
    int k  = (bid >> 2) % 3;
    int b  = bid / 12;
    int t  = threadIdx.x;
    int mg = t >> 4, og = t & 15;  // thread tile: m = mq*64+mg*4+i, o = og*4+j

    // stage W: wT[k] is 4096 floats, flat float4-coalesced.
#pragma unroll
    for (int it = 0; it < 4; ++it) {
        int q = t + it * 256;            // float4 group 0..1023
        int c = q >> 4;
        int o4 = (q & 15) * 4;
        *(float4*)&wL[c][o4] = *(const float4*)&wT[(size_t)k * 4096 + q * 4];
    }

    v2f acc[4][2];
#pragma unroll
    for (int i = 0; i < 4; ++i) { acc[i][0] = (v2f)(0.f); acc[i][1] = (v2f)(0.f); }

    for (int cc = 0; cc < 4; ++cc) {
        __syncthreads();   // W ready (first iter) / previous chunk consumed
        {
            int c = t >> 4, m4 = (t & 15) * 4;
            *(float4*)&xt[c][m4] =
                *(const float4*)&xs_t[((size_t)b * NC + cc * 16 + c) * NM + mq * 64 + m4];
        }
        __syncthreads();
#pragma unroll
        for (int c = 0; c < 16; ++c) {
            float4 a4 = *(const float4*)&xt[c][mg * 4];
            float4 b4 = *(const float4*)&wL[cc * 16 + c][og * 4];
            v2f bp0 = {b4.x, b4.y}, bp1 = {b4.z, b4.w};
            float aa[4] = {a4.x, a4.y, a4.z, a4.w};
#pragma unroll
            for (int i = 0; i < 4; ++i) {
                v2f ai = {aa[i], aa[i]};
                acc[i][0] = __builtin_elementwise_fma(ai, bp0, acc[i][0]);
                acc[i][1] = __builtin_elementwise_fma(ai, bp1, acc[i][1]);
            }
        }
    }

    float* zb = Z + (((size_t)b * 3 + k) * NM + mq * 64) * NC;
#pragma unroll
    for (int i = 0; i < 4; ++i) {
        int m = mg * 4 + i;
        float4 v = {acc[i][0][0], acc[i][0][1], acc[i][1][0], acc[i][1][1]};
        *(float4*)&zb[(size_t)m * NC + og * 4] = v;   // coalesced over og
    }
}

// ---------------------------------------------------------------------------
// Kernel DO (R11): dist + top-3 + output gather/shuffle, fused.
// Block (b,h) computes idx for its 64 tokens (R8 dist body, arithmetic
// verbatim), stores the triples to LDS instead of global, then runs the
// k_out body for the same 64 tokens (Z is ready: k_z2 ran before).
// idx global buffer deleted; one launch + gap removed. All FP op orders
// preserved -> output bitwise identical to R10.
// LDS plan (floats): [0..1024) att | [1024..5120) xsB | [5120..5376) m2l |
// [5376..5440) n2l | [5440..5632) idxL. Out-phase: staged = [0..4160)
// (aliases att+xsB+part of m2l -- all dead after selection; n2l/idxL above).
// ---------------------------------------------------------------------------
static __device__ __forceinline__ unsigned long long packkey(float d, int m) {
    unsigned u = __float_as_uint(d);
    u ^= ((unsigned)((int)u >> 31)) | 0x80000000u;   // monotone float->uint
    return ((unsigned long long)u << 32) | (unsigned)m;
}

__global__ __launch_bounds__(256) void k_do(const float* __restrict__ x,
                                            const float* __restrict__ xs_t,
                                            const float* __restrict__ Z,
                                            const float* __restrict__ bias,
                                            float* __restrict__ out) {
    __shared__ __align__(16) float smem[5632];            // 22528 B
    float (*att)[64]  = (float(*)[64])smem;               // [16][64]
    float (*xsB)[256] = (float(*)[256])(smem + 1024);     // [16][256]
    float* m2l = smem + 5120;                             // [256]
    float* n2l = smem + 5376;                             // [64]
    int  (*idxL)[3] = (int(*)[3])(smem + 5440);           // [64][3]
    float* staged = smem;                                 // [4160] out-phase

    int b = blockIdx.x >> 6;
    int h = blockIdx.x & 63;
    int t = threadIdx.x;
    int r = t >> 4, cl = t & 15;     // token group 0..15, sample lane 0..15

    v2f acc2[4][8];
#pragma unroll
    for (int i = 0; i < 4; ++i)
#pragma unroll
        for (int j = 0; j < 8; ++j) acc2[i][j] = (v2f)(0.f);

    float m2acc = 0.f, n2acc = 0.f;
    const float* xb = x + (size_t)b * 16 * 128 * 128;
    const float* xsb = xs_t + (size_t)b * NC * NM;

    for (int kc = 0; kc < 4; ++kc) {
        __syncthreads();
        // A chunk: att[c1-kc*16][w] from x with unshuffle fold. float2 covers sw={0,1}.
#pragma unroll
        for (int it = 0; it < 2; ++it) {
            int i = t + it * 256;          // 0..511
            int p = i >> 6;                // 0..7 (c1 pair within chunk)
            int wcol = i & 63;
            int c1e = kc * 16 + p * 2;
            int c = c1e >> 2, sh = (c1e >> 1) & 1;
            const float* src = xb + ((size_t)c * 128 + (2 * h + sh)) * 128 + 2 * wcol;
            float2 v = *(const float2*)src;
            att[p * 2 + 0][wcol] = v.x;
            att[p * 2 + 1][wcol] = v.y;
        }
        // B chunk: float4 coalesced from xs_t; quad m4 -> slot (m4&3)*16 + (m4>>2).
#pragma unroll
        for (int it = 0; it < 4; ++it) {
            int g = t + it * 256;          // 0..1023
            int row = g >> 6;              // 0..15
            int m4 = g & 63;               // sample quad id
            int dst = ((((m4 & 3) << 4) | (m4 >> 2))) << 2;
            *(float4*)&xsB[row][dst] =
                *(const float4*)&xsb[(size_t)(kc * 16 + row) * NM + m4 * 4];
        }
        __syncthreads();

        // m2 / n2 partials (sequential ascending c, mul then add like np).
#pragma unroll
        for (int c = 0; c < 16; ++c) {
            float v = xsB[c][t];
            m2acc = __fadd_rn(m2acc, __fmul_rn(v, v));
        }
        if (t < 64) {
#pragma unroll
            for (int c = 0; c < 16; ++c) {
                float v = att[c][t];
                n2acc = __fadd_rn(n2acc, __fmul_rn(v, v));
            }
        }

        // dot accumulation: 4 tokens x 8 sample-pairs (16 samples), paired fma.
#pragma unroll
        for (int k = 0; k < 16; ++k) {
            float4 a0 = *(const float4*)&att[k][r * 4];
            float4 b0 = *(const float4*)&xsB[k][(0 * 16 + cl) * 4];
            float4 b1 = *(const float4*)&xsB[k][(1 * 16 + cl) * 4];
            float4 b2 = *(const float4*)&xsB[k][(2 * 16 + cl) * 4];
            float4 b3 = *(const float4*)&xsB[k][(3 * 16 + cl) * 4];
            v2f bp0 = {b0.x, b0.y}, bp1 = {b0.z, b0.w};
            v2f bp2 = {b1.x, b1.y}, bp3 = {b1.z, b1.w};
            v2f bp4 = {b2.x, b2.y}, bp5 = {b2.z, b2.w};
            v2f bp6 = {b3.x, b3.y}, bp7 = {b3.z, b3.w};
            float aa[4] = {a0.x, a0.y, a0.z, a0.w};
#pragma unroll
            for (int i = 0; i < 4; ++i) {
                v2f ai = {aa[i], aa[i]};
                acc2[i][0] = __builtin_elementwise_fma(ai, bp0, acc2[i][0]);
                acc2[i][1] = __builtin_elementwise_fma(ai, bp1, acc2[i][1]);
                acc2[i][2] = __builtin_elementwise_fma(ai, bp2, acc2[i][2]);
                acc2[i][3] = __builtin_elementwise_fma(ai, bp3, acc2[i][3]);
                acc2[i][4] = __builtin_elementwise_fma(ai, bp4, acc2[i][4]);
                acc2[i][5] = __builtin_elementwise_fma(ai, bp5, acc2[i][5]);
                acc2[i][6] = __builtin_elementwise_fma(ai, bp6, acc2[i][6]);
                acc2[i][7] = __builtin_elementwise_fma(ai, bp7, acc2[i][7]);
            }
        }
    }

    // inverse slot permutation for the m2 store:
    // float index f: slot=f>>2, e=f&3; cl=slot&15, q=slot>>4;
    // m = cl*16 + q*4 + e
    m2l[((t >> 2) & 15) * 16 + (t >> 6) * 4 + (t & 3)] = m2acc;
    if (t < 64) n2l[t] = n2acc;
    __syncthreads();

    // preload this thread's 16 m2 values once (consecutive -> b128 loads)
    float m2r[16];
#pragma unroll
    for (int j = 0; j < 16; ++j) m2r[j] = m2l[cl * 16 + j];

    // selection — fully unrolled so acc stays in VGPRs.
#pragma unroll
    for (int i = 0; i < 4; ++i) {
        int nloc = r * 4 + i;
        float n2v = n2l[nloc];
        float e0d = FLT_MAX, e1d = FLT_MAX, e2d = FLT_MAX;
        int e0m = 0x7fffffff, e1m = 0x7fffffff, e2m = 0x7fffffff;
        // local scan, ascending m => strict compares implement the index
        // tie-break exactly (stable insertion).
#pragma unroll
        for (int j = 0; j < 16; ++j) {
            float dv = acc2[i][j >> 1][j & 1];          // compile-time indices
            float t1 = __fadd_rn(n2v, m2r[j]);          // n2 + m2
            float d = __fadd_rn(t1, -2.0f * dv);        // - 2*dot (2*acc exact)
            int m = cl * 16 + j;
            if (d < e2d) {
                e2d = d; e2m = m;
                if (e2d < e1d) {
                    float td = e1d; int tm = e1m; e1d = e2d; e1m = e2m;
                    e2d = td; e2m = tm;
                    if (e1d < e0d) {
                        float sd = e0d; int sm = e0m; e0d = e1d; e0m = e1m;
                        e1d = sd; e1m = sm;
                    }
                }
            }
        }
        // pack to sortable u64 keys (local list is sorted ascending)
        unsigned long long k0 = packkey(e0d, e0m);
        unsigned long long k1 = packkey(e1d, e1m);
        unsigned long long k2 = packkey(e2d, e2m);
        // butterfly merge of sorted top-3 lists over 16 lanes (4 stages)
#pragma unroll
        for (int mask = 1; mask <= 8; mask <<= 1) {
            unsigned long long q0 = __shfl_xor(k0, mask);
            unsigned long long q1 = __shfl_xor(k1, mask);
            unsigned long long q2 = __shfl_xor(k2, mask);
            unsigned long long clo = k0 < q0 ? k0 : q0;
            unsigned long long chi = k0 < q0 ? q0 : k0;
            unsigned long long dlo = k1 < q1 ? k1 : q1;
            unsigned long long dhi = k1 < q1 ? q1 : k1;
            unsigned long long f2  = k2 < q2 ? k2 : q2;
            unsigned long long elo = chi < dlo ? chi : dlo;
            unsigned long long ehi = chi < dlo ? dlo : chi;
            unsigned long long g2  = dhi < f2 ? dhi : f2;
            k0 = clo;
            k1 = elo;
            k2 = ehi < g2 ? ehi : g2;
        }
        if (cl == 0) {
            idxL[nloc][0] = (int)(unsigned)(k0 & 0xffffffffu);
            idxL[nloc][1] = (int)(unsigned)(k1 & 0xffffffffu);
            idxL[nloc][2] = (int)(unsigned)(k2 & 0xffffffffu);
        }
    }
    __syncthreads();   // idxL ready; att/xsB/m2l dead -> staged may alias

    // ---- out-phase (k_out body, arithmetic verbatim) ----
    {
        int o = t & 63, wv = t >> 6;
        float bv = bias[o];
        const float* zb = Z + (size_t)b * 3 * NM * NC;
        for (int ti = 0; ti < 16; ++ti) {
            int w = wv * 16 + ti;                      // token = h*64 + w
            int i0 = idxL[w][0], i1 = idxL[w][1], i2 = idxL[w][2];
            float v = bv + zb[(size_t)i0 * NC + o]
                         + zb[(size_t)(NM + i1) * NC + o]
                         + zb[(size_t)(2 * NM + i2) * NC + o];
            staged[o * 65 + w] = v;                    // (o+w)%32 banks: conflict-free
        }
        __syncthreads();
        float* ob = out + (size_t)b * 16 * 128 * 128;
#pragma unroll
        for (int it = 0; it < 16; ++it) {
            int flat = t + it * 256;                   // 0..4095
            int W = flat & 127, sh = (flat >> 7) & 1, cc = flat >> 8;
            int oo = cc * 4 + sh * 2 + (W & 1);
            ob[((size_t)cc * 128 + 2 * h + sh) * 128 + W] = staged[oo * 65 + (W >> 1)];
        }
    }
}

// ---------------------------------------------------------------------------
extern "C" void kernel_launch(void* const* d_in, const int* in_sizes, int n_in,
                              void* d_out, int out_size, void* d_ws, size_t ws_size,
                              hipStream_t stream) {
    const float* x    = (const float*)d_in[0];
    const float* w    = (const float*)d_in[1];
    const float* bias = (const float*)d_in[2];
    float* out = (float*)d_out;
    float* ws  = (float*)d_ws;

    // workspace layout (floats):
    float* xs_t = ws;                          // 32*64*256   = 524288
    float* Z    = ws + 524288;                 // 32*3*256*64 = 1572864
    float* wT   = ws + 2097152;                // 3*64*64     = 12288
    // total ~8.4 MB

    hipLaunchKernelGGL(k_pre, dim3(NB * 16 + 48), dim3(256), 0, stream,
                       x, w, wT, xs_t);
    hipLaunchKernelGGL(k_z2,  dim3(NB * 3 * 4),   dim3(256), 0, stream,
                       xs_t, wT, Z);
    hipLaunchKernelGGL(k_do,  dim3(NB * 64),      dim3(256), 0, stream,
                       x, xs_t, Z, bias, out);
}